// Round 8
// baseline (1057.447 us; speedup 1.0000x reference)
//
#include <hip/hip_runtime.h>

#define RNN_B 64
#define RNN_T 1024
#define RNN_D 256
#define RNN_H 256
#define NB 8                               // batches per scan workgroup
#define NSCAN 8                            // scan workgroups
#define GEMM_TB 32                         // t-rows per gemm block
#define NGEMM (RNN_B * RNN_T / GEMM_TB)    // 2048
#define NCHUNK 16                          // 64 timesteps per flag chunk
#define FLAG_TARGET 2                      // gemm blocks per (b,chunk)

typedef __attribute__((ext_vector_type(8))) short bf16x8;
typedef __attribute__((ext_vector_type(4))) float f32x4;

__device__ __forceinline__ unsigned short f32_to_bf16_rne(float f) {
  unsigned u = __builtin_bit_cast(unsigned, f);
  u += 0x7fffu + ((u >> 16) & 1u);
  return (unsigned short)(u >> 16);
}

// branch-free tanh: 1 - 2/(exp(2x)+1); exact at +/-inf, ~1e-6 abs err
__device__ __forceinline__ float tanh_fast(float x) {
  const float t = __expf(2.0f * x);
  const float r = __builtin_amdgcn_rcpf(t + 1.0f);
  return fmaf(-2.0f, r, 1.0f);
}

// swizzled u16 index of h[batch][col]; row stride 512B, XOR spreads rows
// across 16B bank-slots.
__device__ __forceinline__ int hidx(int batch, int col) {
  return ((batch & 7) * 512 + ((col * 2) ^ ((batch & 7) << 4))) >> 1;
}

__device__ __forceinline__ void wg_barrier_lds_only() {
  // drain LDS ops only; deliberately NOT vmcnt -> global xp prefetch and h
  // stores stay in flight across steps (avoids __syncthreads' vmcnt(0) drain)
  asm volatile("s_waitcnt lgkmcnt(0)" ::: "memory");
  __builtin_amdgcn_sched_barrier(0);
  __builtin_amdgcn_s_barrier();
  __builtin_amdgcn_sched_barrier(0);
}

// spin until chunk c of all NB batches in group bg is produced (ACQUIRE so
// the subsequent xp reads see the producer's stores, cross-XCD safe)
__device__ __forceinline__ void wait_chunk(const int* flags, int bg, int c) {
#pragma unroll 1
  for (int b = 0; b < NB; ++b) {
    const int* f = &flags[(bg * NB + b) * NCHUNK + c];
#pragma unroll 1
    while (__hip_atomic_load(f, __ATOMIC_ACQUIRE, __HIP_MEMORY_SCOPE_AGENT) <
           FLAG_TARGET) {
      __builtin_amdgcn_s_sleep(2);
    }
  }
}

// ---------------------------------------------------------------------------
// One recurrence step (identical math/layout to R7). Swapped-operand MFMA:
// S^T = Wh^T (A') x h^T (B'). 16 waves; wave wid owns ONE outcol tile.
// Lanes with lrow >= NB are exec-masked off LDS/global; their MFMA output is
// garbage, never stored. acc seeded with xp (C-in); even/odd kc chains.
// ---------------------------------------------------------------------------
template <int RD, int TOFF>
__device__ __forceinline__ void rnn_step(
    unsigned short (*hb)[NB * 256], const bf16x8 (&wfrag)[8],
    f32x4& xc, f32x4& xn, const float* xp_ld, float* h_st, float* hl_st,
    bool last, bool act, int lrow, int lq, int wid) {
  // 1) B'-fragments of h from LDS first (critical path), masked to NB rows
  bf16x8 hf[8];
  if (act) {
#pragma unroll
    for (int kc = 0; kc < 8; ++kc) {
      const int off = (lrow * 512 + ((kc * 64 + lq * 16) ^ (lrow << 4))) >> 1;
      hf[kc] = *reinterpret_cast<const bf16x8*>(&hb[RD][off]);
    }
    // 2) prefetch xp for the NEXT step (consumed after the next barrier)
    xn = *reinterpret_cast<const f32x4*>(&xp_ld[TOFF * RNN_H]);
  }

  // 3) MFMA: two independent chains (even/odd kc), depth 4
  f32x4 accE = xc;
  f32x4 accO = {0.f, 0.f, 0.f, 0.f};
  __builtin_amdgcn_s_setprio(1);
#pragma unroll
  for (int kc = 0; kc < 8; kc += 2) {
    accE = __builtin_amdgcn_mfma_f32_16x16x32_bf16(wfrag[kc], hf[kc], accE, 0,
                                                   0, 0);
    accO = __builtin_amdgcn_mfma_f32_16x16x32_bf16(wfrag[kc + 1], hf[kc + 1],
                                                   accO, 0, 0, 0);
  }
  __builtin_amdgcn_s_setprio(0);

  // 4) tanh; float4 global store; packed bf16 b64 -> other LDS buffer
  f32x4 h;
#pragma unroll
  for (int r = 0; r < 4; ++r) h[r] = tanh_fast(accE[r] + accO[r]);
  if (act) {
    *reinterpret_cast<f32x4*>(&h_st[TOFF * RNN_H]) = h;
    if (last) *reinterpret_cast<f32x4*>(hl_st) = h;

    unsigned p0, p1;
    asm("v_cvt_pk_bf16_f32 %0, %1, %2" : "=v"(p0) : "v"(h[0]), "v"(h[1]));
    asm("v_cvt_pk_bf16_f32 %0, %1, %2" : "=v"(p1) : "v"(h[2]), "v"(h[3]));
    uint2 pk; pk.x = p0; pk.y = p1;
    const int byte = lrow * 512 + ((wid * 32 + lq * 8) ^ (lrow << 4));
    *reinterpret_cast<uint2*>(&hb[RD ^ 1][byte >> 1]) = pk;
  }

  // 5) LDS-only barrier (global ops remain in flight)
  wg_barrier_lds_only();
}

// ---------------------------------------------------------------------------
// Fused kernel: blocks [0,NSCAN) = recurrence consumers (one per 8 batches);
// blocks [NSCAN, NSCAN+NGEMM) = xp GEMM producers (t-major dispatch order so
// early timesteps of ALL batches complete first). Producers signal per
// (batch, 64-step chunk) flags; consumers ACQUIRE-spin one chunk ahead of
// their prefetch window.
// ---------------------------------------------------------------------------
__global__ __launch_bounds__(1024, 4) void rnn_fused(
    const float* __restrict__ x, const float* __restrict__ Wx,
    const float* __restrict__ bias, const float* __restrict__ Wh,
    const float* __restrict__ h0, float* out, float* h_last, int* flags) {
  __shared__ __align__(16) char smem[GEMM_TB * RNN_D * 4];  // 32KB arena

  if (blockIdx.x >= NSCAN) {
    // =================== GEMM producer: 32 t-rows of one batch ==========
    const int g = blockIdx.x - NSCAN;
    const int b = g & (RNN_B - 1);   // consecutive g -> same tblk, diff b
    const int tblk = g >> 6;         // 0..31
    const int t0 = tblk * GEMM_TB;
    const int sub = threadIdx.x >> 8;  // 0..3 : 8 t-rows each
    const int j = threadIdx.x & 255;   // output column
    float* xs = reinterpret_cast<float*>(smem);  // [32][256]

    const float4* xg =
        reinterpret_cast<const float4*>(x + ((size_t)b * RNN_T + t0) * RNN_D);
    float4* xsv = reinterpret_cast<float4*>(xs);
    xsv[threadIdx.x] = xg[threadIdx.x];
    xsv[threadIdx.x + 1024] = xg[threadIdx.x + 1024];
    __syncthreads();

    const float bj = bias[j];
    float acc[8];
#pragma unroll
    for (int r = 0; r < 8; ++r) acc[r] = bj;

    const float* xrow = xs + sub * 8 * RNN_D;
    for (int k = 0; k < RNN_D; k += 4) {
      const float w0 = Wx[(size_t)(k + 0) * RNN_H + j];
      const float w1 = Wx[(size_t)(k + 1) * RNN_H + j];
      const float w2 = Wx[(size_t)(k + 2) * RNN_H + j];
      const float w3 = Wx[(size_t)(k + 3) * RNN_H + j];
#pragma unroll
      for (int r = 0; r < 8; ++r) {
        const float4 xv = *reinterpret_cast<const float4*>(&xrow[r * RNN_D + k]);
        acc[r] = fmaf(xv.x, w0, acc[r]);
        acc[r] = fmaf(xv.y, w1, acc[r]);
        acc[r] = fmaf(xv.z, w2, acc[r]);
        acc[r] = fmaf(xv.w, w3, acc[r]);
      }
    }
    float* orow = out + ((size_t)b * RNN_T + t0 + sub * 8) * RNN_H + j;
#pragma unroll
    for (int r = 0; r < 8; ++r) orow[(size_t)r * RNN_H] = acc[r];

    __syncthreads();  // all sub-blocks' stores issued
    if (threadIdx.x == 0) {
      __hip_atomic_fetch_add(&flags[b * NCHUNK + (tblk >> 1)], 1,
                             __ATOMIC_RELEASE, __HIP_MEMORY_SCOPE_AGENT);
    }
    return;
  }

  // =================== scan consumer (identical to R7 core) =============
  unsigned short(*hb)[NB * 256] =
      reinterpret_cast<unsigned short(*)[NB * 256]>(smem);

  const int bg = blockIdx.x;     // batch group 0..7
  const int tid = threadIdx.x;
  const int wid = tid >> 6;      // 0..15 = outcol tile
  const int lane = tid & 63;
  const int lrow = lane & 15;    // batch (if < NB) / A' m-index
  const int lq = lane >> 4;      // k-quad / C row-quad
  const bool act = lrow < NB;

  // ---- one-time: Wh^T A'-fragments (f32 -> bf16, RNE) into VGPRs -------
  bf16x8 wfrag[8];
  {
    const int col = wid * 16 + lrow;
#pragma unroll
    for (int kc = 0; kc < 8; ++kc) {
      bf16x8 v;
#pragma unroll
      for (int j = 0; j < 8; ++j) {
        const int k = kc * 32 + lq * 8 + j;
        v[j] = (short)f32_to_bf16_rne(Wh[(size_t)k * RNN_H + col]);
      }
      wfrag[kc] = v;
    }
  }

  // ---- one-time: h0 -> hb[0] (bf16, swizzled); 8 rows x 256 cols -------
  {
    const int b = tid >> 7;            // 0..7
    const int c0 = (tid & 127) * 2;    // 2 cols per thread
    hb[0][hidx(b, c0 + 0)] =
        f32_to_bf16_rne(h0[(size_t)(bg * NB + b) * RNN_H + c0 + 0]);
    hb[0][hidx(b, c0 + 1)] =
        f32_to_bf16_rne(h0[(size_t)(bg * NB + b) * RNN_H + c0 + 1]);
  }

  // wait for chunks 0 and 1 (covers xp[t=0] seed + prefetch through t=64)
  wait_chunk(flags, bg, 0);
  wait_chunk(flags, bg, 1);

  // per-lane global pointers: batch = lrow (if act), 4 consecutive cols
  float* outb = out + (size_t)bg * NB * RNN_T * RNN_H;
  const int col0 = wid * 16 + lq * 4;
  float* hbase = outb + (size_t)(lrow & 7) * RNN_T * RNN_H + col0;
  const float* xp_ld = hbase + RNN_H;  // -> xp[t=1]
  float* h_st = hbase;                 // -> h[t=0]
  float* hl_st = h_last + (size_t)(bg * NB + (lrow & 7)) * RNN_H + col0;
  f32x4 xA, xB;
  if (act) xA = *reinterpret_cast<const f32x4*>(hbase);  // xp[t=0]

  wg_barrier_lds_only();  // h0 staging visible

#pragma unroll 1
  for (int t = 0; t < RNN_T; t += 2) {
    if ((t & 63) == 0 && t > 0) {
      const int c = (t >> 6) + 1;  // one chunk ahead of prefetch window
      if (c < NCHUNK) wait_chunk(flags, bg, c);
    }
    const bool lastp = (t == RNN_T - 2);
    rnn_step<0, 0>(hb, wfrag, xA, xB, xp_ld, h_st, hl_st, false, act, lrow, lq,
                   wid);
    rnn_step<1, 1>(hb, wfrag, xB, xA, xp_ld, h_st, hl_st, lastp, act, lrow, lq,
                   wid);
    xp_ld += 2 * RNN_H;
    h_st += 2 * RNN_H;
  }
}

extern "C" void kernel_launch(void* const* d_in, const int* in_sizes, int n_in,
                              void* d_out, int out_size, void* d_ws, size_t ws_size,
                              hipStream_t stream) {
  const float* x = (const float*)d_in[0];
  const float* h0 = (const float*)d_in[1];
  const float* Wx = (const float*)d_in[2];
  const float* Wh = (const float*)d_in[3];
  const float* bias = (const float*)d_in[4];
  float* out = (float*)d_out;
  float* h_last = out + (size_t)RNN_B * RNN_T * RNN_H;
  int* flags = (int*)d_ws;

  hipMemsetAsync(flags, 0, RNN_B * NCHUNK * sizeof(int), stream);
  rnn_fused<<<NSCAN + NGEMM, 1024, 0, stream>>>(x, Wx, bias, Wh, h0, out,
                                                h_last, flags);
}

// Round 9
// 823.509 us; speedup vs baseline: 1.2841x; 1.2841x over previous
//
#include <hip/hip_runtime.h>

#define RNN_B 64
#define RNN_T 1024
#define RNN_D 256
#define RNN_H 256
#define NB 8          // batches per scan workgroup
#define GEMM_ROWS 16  // (b*t) rows per gemm block

typedef __attribute__((ext_vector_type(8))) short bf16x8;
typedef __attribute__((ext_vector_type(4))) float f32x4;

__device__ __forceinline__ unsigned short f32_to_bf16_rne(float f) {
  unsigned u = __builtin_bit_cast(unsigned, f);
  u += 0x7fffu + ((u >> 16) & 1u);
  return (unsigned short)(u >> 16);
}

// branch-free tanh: 1 - 2/(exp(2x)+1); exact at +/-inf, ~1e-6 abs err
__device__ __forceinline__ float tanh_fast(float x) {
  const float t = __expf(2.0f * x);
  const float r = __builtin_amdgcn_rcpf(t + 1.0f);
  return fmaf(-2.0f, r, 1.0f);
}

// swizzled u16 index of h[batch][col]; row stride 512B, XOR spreads rows
// across 16B bank-slots.
__device__ __forceinline__ int hidx(int batch, int col) {
  return ((batch & 7) * 512 + ((col * 2) ^ ((batch & 7) << 4))) >> 1;
}

__device__ __forceinline__ void wg_barrier_lds_only() {
  // drain LDS ops only; deliberately NOT vmcnt -> global xp prefetch and h
  // stores stay in flight across steps (avoids __syncthreads' vmcnt(0) drain)
  asm volatile("s_waitcnt lgkmcnt(0)" ::: "memory");
  __builtin_amdgcn_sched_barrier(0);
  __builtin_amdgcn_s_barrier();
  __builtin_amdgcn_sched_barrier(0);
}

// ---------------------------------------------------------------------------
// Kernel 1 (v2): xp[b,t,:] = x[b,t,:] @ Wx + b  (into the hs region of out)
// 16 rows/block (Wx L2 traffic halved vs 8), k-unroll 8 with hoisted Wx
// loads so the L2 load latency pipelines instead of serializing per-4-k.
// ---------------------------------------------------------------------------
__global__ __launch_bounds__(256) void xp_gemm_kernel(
    const float* __restrict__ x, const float* __restrict__ Wx,
    const float* __restrict__ bias, float* __restrict__ xp) {
  __shared__ float xs[GEMM_ROWS][RNN_D];  // 16 KB
  const int j = threadIdx.x;              // output column 0..255
  const size_t row0 = (size_t)blockIdx.x * GEMM_ROWS;

  // stage 16 x-rows (4096 f32 = 1024 float4; 4 per thread)
  const float4* xg = reinterpret_cast<const float4*>(x + row0 * RNN_D);
  float4* xsv = reinterpret_cast<float4*>(&xs[0][0]);
#pragma unroll
  for (int i = 0; i < 4; ++i) xsv[j + 256 * i] = xg[j + 256 * i];
  __syncthreads();

  const float bj = bias[j];
  float acc[GEMM_ROWS];
#pragma unroll
  for (int r = 0; r < GEMM_ROWS; ++r) acc[r] = bj;

#pragma unroll 1
  for (int k = 0; k < RNN_D; k += 8) {
    float w[8];
#pragma unroll
    for (int u = 0; u < 8; ++u) w[u] = Wx[(size_t)(k + u) * RNN_H + j];
#pragma unroll
    for (int r = 0; r < GEMM_ROWS; ++r) {
      const float4 x0 = *reinterpret_cast<const float4*>(&xs[r][k]);
      const float4 x1 = *reinterpret_cast<const float4*>(&xs[r][k + 4]);
      acc[r] = fmaf(x0.x, w[0], acc[r]);
      acc[r] = fmaf(x0.y, w[1], acc[r]);
      acc[r] = fmaf(x0.z, w[2], acc[r]);
      acc[r] = fmaf(x0.w, w[3], acc[r]);
      acc[r] = fmaf(x1.x, w[4], acc[r]);
      acc[r] = fmaf(x1.y, w[5], acc[r]);
      acc[r] = fmaf(x1.z, w[6], acc[r]);
      acc[r] = fmaf(x1.w, w[7], acc[r]);
    }
  }
#pragma unroll
  for (int r = 0; r < GEMM_ROWS; ++r) xp[(row0 + r) * RNN_H + j] = acc[r];
}

// ---------------------------------------------------------------------------
// One recurrence step (R7 core + depth-4 xp pipeline). Swapped-operand MFMA:
// S^T = Wh^T (A') x h^T (B'). 16 waves; wave wid owns ONE outcol tile.
// Lanes with lrow >= NB are exec-masked off LDS/global; their MFMA output is
// garbage, never stored. acc seeded with xp (C-in); even/odd kc chains.
// SLOT = step index within the 4-step unroll (static -> xq stays in VGPRs);
// RD = SLOT&1 is the LDS h buffer. xp_base points at row t+4 (load target
// row t+4+SLOT); h_base points at row t (store row t+SLOT).
// ---------------------------------------------------------------------------
template <int SLOT>
__device__ __forceinline__ void rnn_step(
    unsigned short (&hb)[2][NB * 256], const bf16x8 (&wfrag)[8],
    f32x4 (&xq)[4], const float* xp_base, float* h_base, float* hl_st,
    bool last, bool act, int lrow, int lq, int wid) {
  constexpr int RD = SLOT & 1;
  const f32x4 xc = xq[SLOT];  // consume (loaded 4 steps ago)

  // 1) B'-fragments of h from LDS first (critical path), masked to NB rows
  bf16x8 hf[8];
  if (act) {
#pragma unroll
    for (int kc = 0; kc < 8; ++kc) {
      const int off = (lrow * 512 + ((kc * 64 + lq * 16) ^ (lrow << 4))) >> 1;
      hf[kc] = *reinterpret_cast<const bf16x8*>(&hb[RD][off]);
    }
    // 2) refill slot: prefetch xp for step t+SLOT+4 (consumed 4 steps later)
    xq[SLOT] = *reinterpret_cast<const f32x4*>(&xp_base[SLOT * RNN_H]);
  }

  // 3) MFMA: two independent chains (even/odd kc), depth 4
  f32x4 accE = xc;
  f32x4 accO = {0.f, 0.f, 0.f, 0.f};
  __builtin_amdgcn_s_setprio(1);
#pragma unroll
  for (int kc = 0; kc < 8; kc += 2) {
    accE = __builtin_amdgcn_mfma_f32_16x16x32_bf16(wfrag[kc], hf[kc], accE, 0,
                                                   0, 0);
    accO = __builtin_amdgcn_mfma_f32_16x16x32_bf16(wfrag[kc + 1], hf[kc + 1],
                                                   accO, 0, 0, 0);
  }
  __builtin_amdgcn_s_setprio(0);

  // 4) tanh; float4 global store; packed bf16 b64 -> other LDS buffer
  f32x4 h;
#pragma unroll
  for (int r = 0; r < 4; ++r) h[r] = tanh_fast(accE[r] + accO[r]);
  if (act) {
    *reinterpret_cast<f32x4*>(&h_base[SLOT * RNN_H]) = h;
    if (last) *reinterpret_cast<f32x4*>(hl_st) = h;

    unsigned p0, p1;
    asm("v_cvt_pk_bf16_f32 %0, %1, %2" : "=v"(p0) : "v"(h[0]), "v"(h[1]));
    asm("v_cvt_pk_bf16_f32 %0, %1, %2" : "=v"(p1) : "v"(h[2]), "v"(h[3]));
    uint2 pk; pk.x = p0; pk.y = p1;
    const int byte = lrow * 512 + ((wid * 32 + lq * 8) ^ (lrow << 4));
    *reinterpret_cast<uint2*>(&hb[RD ^ 1][byte >> 1]) = pk;
  }

  // 5) LDS-only barrier (global ops remain in flight)
  wg_barrier_lds_only();
}

// ---------------------------------------------------------------------------
// Kernel 2: MFMA recurrence. 8 WGs x 8 batches, 16 waves (1024 thr) each
// -> 4 waves/SIMD; xp prefetched 4 steps deep.
// ---------------------------------------------------------------------------
__global__ __launch_bounds__(1024, 4) void rnn_rec_mfma(
    const float* __restrict__ Wh, const float* __restrict__ h0, float* out,
    float* h_last) {
  __shared__ unsigned short hb[2][NB * 256];

  const int bg = blockIdx.x;     // batch group 0..7
  const int tid = threadIdx.x;
  const int wid = tid >> 6;      // 0..15 = outcol tile
  const int lane = tid & 63;
  const int lrow = lane & 15;    // batch (if < NB) / A' m-index
  const int lq = lane >> 4;      // k-quad / C row-quad
  const bool act = lrow < NB;

  // ---- one-time: Wh^T A'-fragments (f32 -> bf16, RNE) into VGPRs -------
  bf16x8 wfrag[8];
  {
    const int col = wid * 16 + lrow;
#pragma unroll
    for (int kc = 0; kc < 8; ++kc) {
      bf16x8 v;
#pragma unroll
      for (int j = 0; j < 8; ++j) {
        const int k = kc * 32 + lq * 8 + j;
        v[j] = (short)f32_to_bf16_rne(Wh[(size_t)k * RNN_H + col]);
      }
      wfrag[kc] = v;
    }
  }

  // ---- one-time: h0 -> hb[0] (bf16, swizzled); 8 rows x 256 cols -------
  {
    const int b = tid >> 7;            // 0..7
    const int c0 = (tid & 127) * 2;    // 2 cols per thread
    hb[0][hidx(b, c0 + 0)] =
        f32_to_bf16_rne(h0[(size_t)(bg * NB + b) * RNN_H + c0 + 0]);
    hb[0][hidx(b, c0 + 1)] =
        f32_to_bf16_rne(h0[(size_t)(bg * NB + b) * RNN_H + c0 + 1]);
  }

  // per-lane global pointers: batch = lrow (if act), 4 consecutive cols
  float* outb = out + (size_t)bg * NB * RNN_T * RNN_H;
  const int col0 = wid * 16 + lq * 4;
  float* hbase = outb + (size_t)(lrow & 7) * RNN_T * RNN_H + col0;
  float* hl_st = h_last + (size_t)(bg * NB + (lrow & 7)) * RNN_H + col0;

  // prologue: xp rows 0..3 into the 4-slot register pipeline
  f32x4 xq[4];
  if (act) {
#pragma unroll
    for (int s = 0; s < 4; ++s)
      xq[s] = *reinterpret_cast<const f32x4*>(&hbase[s * RNN_H]);
  }
  const float* xp_base = hbase + 4 * RNN_H;  // -> xp row t+4
  float* h_base = hbase;                     // -> h row t

  wg_barrier_lds_only();  // h0 staging visible

#pragma unroll 1
  for (int t = 0; t < RNN_T; t += 4) {
    const bool lastp = (t == RNN_T - 4);
    rnn_step<0>(hb, wfrag, xq, xp_base, h_base, hl_st, false, act, lrow, lq, wid);
    rnn_step<1>(hb, wfrag, xq, xp_base, h_base, hl_st, false, act, lrow, lq, wid);
    rnn_step<2>(hb, wfrag, xq, xp_base, h_base, hl_st, false, act, lrow, lq, wid);
    rnn_step<3>(hb, wfrag, xq, xp_base, h_base, hl_st, lastp, act, lrow, lq, wid);
    xp_base += 4 * RNN_H;
    h_base += 4 * RNN_H;
  }
}

extern "C" void kernel_launch(void* const* d_in, const int* in_sizes, int n_in,
                              void* d_out, int out_size, void* d_ws, size_t ws_size,
                              hipStream_t stream) {
  const float* x = (const float*)d_in[0];
  const float* h0 = (const float*)d_in[1];
  const float* Wx = (const float*)d_in[2];
  const float* Wh = (const float*)d_in[3];
  const float* bias = (const float*)d_in[4];
  float* out = (float*)d_out;
  float* h_last = out + (size_t)RNN_B * RNN_T * RNN_H;

  xp_gemm_kernel<<<RNN_B * RNN_T / GEMM_ROWS, 256, 0, stream>>>(x, Wx, bias,
                                                                out);
  rnn_rec_mfma<<<RNN_B / NB, 1024, 0, stream>>>(Wh, h0, out, h_last);
}

// Round 10
// 700.293 us; speedup vs baseline: 1.5100x; 1.1759x over previous
//
#include <hip/hip_runtime.h>

#define RNN_B 64
#define RNN_T 1024
#define RNN_D 256
#define RNN_H 256
#define NB 8           // batches per scan workgroup
#define GEMM_ROWS 64   // (b,t) rows per gemm block

typedef __attribute__((ext_vector_type(8))) short bf16x8;
typedef __attribute__((ext_vector_type(4))) float f32x4;

__device__ __forceinline__ unsigned short f32_to_bf16_rne(float f) {
  unsigned u = __builtin_bit_cast(unsigned, f);
  u += 0x7fffu + ((u >> 16) & 1u);
  return (unsigned short)(u >> 16);
}

// branch-free tanh: 1 - 2/(exp(2x)+1); exact at +/-inf, ~1e-6 abs err
__device__ __forceinline__ float tanh_fast(float x) {
  const float t = __expf(2.0f * x);
  const float r = __builtin_amdgcn_rcpf(t + 1.0f);
  return fmaf(-2.0f, r, 1.0f);
}

// swizzled u16 index of h[batch][col]; row stride 512B, XOR spreads rows
// across 16B bank-slots.
__device__ __forceinline__ int hidx(int batch, int col) {
  return ((batch & 7) * 512 + ((col * 2) ^ ((batch & 7) << 4))) >> 1;
}

__device__ __forceinline__ void wg_barrier_lds_only() {
  // drain LDS ops only; deliberately NOT vmcnt -> global xp prefetch and h
  // stores stay in flight across steps (avoids __syncthreads' vmcnt(0) drain)
  asm volatile("s_waitcnt lgkmcnt(0)" ::: "memory");
  __builtin_amdgcn_sched_barrier(0);
  __builtin_amdgcn_s_barrier();
  __builtin_amdgcn_sched_barrier(0);
}

// ---------------------------------------------------------------------------
// Kernel 0: Wx (f32 [k][col]) -> Wxb (bf16, fragment order [col][kc][lq][j])
// so gemm waves load A'-frags as coalesced 16B chunks.
// ---------------------------------------------------------------------------
__global__ __launch_bounds__(1024) void wx_prep_kernel(
    const float* __restrict__ Wx, unsigned short* __restrict__ Wxb) {
  const int g = blockIdx.x * 1024 + threadIdx.x;  // 8192 frags
  const int lq = g & 3;
  const int kc = (g >> 2) & 7;
  const int col = g >> 5;
  unsigned short v[8];
#pragma unroll
  for (int j = 0; j < 8; ++j) {
    const int k = kc * 32 + lq * 8 + j;
    v[j] = f32_to_bf16_rne(Wx[(size_t)k * RNN_H + col]);
  }
  *reinterpret_cast<uint4*>(&Wxb[(size_t)g * 8]) =
      *reinterpret_cast<const uint4*>(v);
}

// ---------------------------------------------------------------------------
// Kernel 1 (v3, MFMA): xp^T = Wx^T (A', VGPRs from Wxb) x x^T (B', LDS bf16).
// 1024 blocks x 1024 thr (16 waves); block handles 64 (b,t) rows.
// Stage: x f32 -> bf16 LDS [64 rows][256 k], row stride 512B, XOR swizzle
// byte ^= (row&7)<<4 (same verified pattern as the scan's h buffer).
// Wave wid owns outcol tile [wid*16, wid*16+16); 4 row-groups of 16.
// acc seeded with bias (C-in). D: t-row = lane&15, outcol = wid*16+lq*4+r
// -> f32x4 stores.
// ---------------------------------------------------------------------------
__global__ __launch_bounds__(1024) void xp_gemm_mfma(
    const float* __restrict__ x, const unsigned short* __restrict__ Wxb,
    const float* __restrict__ bias, float* __restrict__ xp) {
  __shared__ unsigned short xs[GEMM_ROWS * 256];  // 32 KB

  const int tid = threadIdx.x;
  const int wid = tid >> 6;      // 0..15 = outcol tile
  const int lane = tid & 63;
  const int lrow = lane & 15;    // n-index: t-row within group
  const int lq = lane >> 4;      // k-quad / D row-quad
  const size_t row0 = (size_t)blockIdx.x * GEMM_ROWS;

  // A'-frags from Wxb: coalesced 16B loads (issue first, latency overlaps
  // with the staging below)
  bf16x8 wfrag[8];
  {
    const int col = wid * 16 + lrow;
#pragma unroll
    for (int kc = 0; kc < 8; ++kc)
      wfrag[kc] = *reinterpret_cast<const bf16x8*>(
          &Wxb[(size_t)((col * 8 + kc) * 4 + lq) * 8]);
  }
  const f32x4 bseed = *reinterpret_cast<const f32x4*>(&bias[wid * 16 + lq * 4]);

  // stage 64 x-rows as bf16 (each thread: 16 cols of one row)
  {
    const int row = tid >> 4;            // 0..63
    const int c16 = (tid & 15) * 16;     // col base
    const float* src = x + (row0 + row) * RNN_D + c16;
    unsigned p[8];
#pragma unroll
    for (int q = 0; q < 4; ++q) {
      const f32x4 v = *reinterpret_cast<const f32x4*>(src + 4 * q);
      asm("v_cvt_pk_bf16_f32 %0, %1, %2" : "=v"(p[2 * q]) : "v"(v[0]), "v"(v[1]));
      asm("v_cvt_pk_bf16_f32 %0, %1, %2" : "=v"(p[2 * q + 1]) : "v"(v[2]), "v"(v[3]));
    }
    const int swz = (row & 7) << 4;
    const int b0 = row * 512 + ((c16 * 2) ^ swz);
    const int b1 = row * 512 + ((c16 * 2 + 16) ^ swz);
    *reinterpret_cast<uint4*>(&xs[b0 >> 1]) = *reinterpret_cast<uint4*>(&p[0]);
    *reinterpret_cast<uint4*>(&xs[b1 >> 1]) = *reinterpret_cast<uint4*>(&p[4]);
  }
  __syncthreads();

#pragma unroll
  for (int rg = 0; rg < GEMM_ROWS / 16; ++rg) {
    // B'-frags: row = rg*16 + lrow, k-slice = kc*32 + lq*8 (+8)
    bf16x8 hf[8];
#pragma unroll
    for (int kc = 0; kc < 8; ++kc) {
      const int off =
          ((rg * 16 + lrow) * 512 + ((kc * 64 + lq * 16) ^ ((lrow & 7) << 4))) >> 1;
      hf[kc] = *reinterpret_cast<const bf16x8*>(&xs[off]);
    }
    f32x4 accE = bseed;
    f32x4 accO = {0.f, 0.f, 0.f, 0.f};
#pragma unroll
    for (int kc = 0; kc < 8; kc += 2) {
      accE = __builtin_amdgcn_mfma_f32_16x16x32_bf16(wfrag[kc], hf[kc], accE,
                                                     0, 0, 0);
      accO = __builtin_amdgcn_mfma_f32_16x16x32_bf16(wfrag[kc + 1], hf[kc + 1],
                                                     accO, 0, 0, 0);
    }
    const f32x4 r = accE + accO;
    float* dst = xp + (row0 + rg * 16 + lrow) * RNN_H + wid * 16 + lq * 4;
    *reinterpret_cast<f32x4*>(dst) = r;
  }
}

// ---------------------------------------------------------------------------
// One recurrence step (identical to R9). Swapped-operand MFMA:
// S^T = Wh^T (A') x h^T (B'). 16 waves; wave wid owns ONE outcol tile.
// Lanes with lrow >= NB are exec-masked off LDS/global. acc seeded with xp
// (C-in); even/odd kc chains. SLOT = step index in 4-step unroll; RD=SLOT&1.
// ---------------------------------------------------------------------------
template <int SLOT>
__device__ __forceinline__ void rnn_step(
    unsigned short (&hb)[2][NB * 256], const bf16x8 (&wfrag)[8],
    f32x4 (&xq)[4], const float* xp_base, float* h_base, float* hl_st,
    bool last, bool act, int lrow, int lq, int wid) {
  constexpr int RD = SLOT & 1;
  const f32x4 xc = xq[SLOT];  // consume (loaded 4 steps ago)

  // 1) B'-fragments of h from LDS first (critical path), masked to NB rows
  bf16x8 hf[8];
  if (act) {
#pragma unroll
    for (int kc = 0; kc < 8; ++kc) {
      const int off = (lrow * 512 + ((kc * 64 + lq * 16) ^ (lrow << 4))) >> 1;
      hf[kc] = *reinterpret_cast<const bf16x8*>(&hb[RD][off]);
    }
    // 2) refill slot: prefetch xp for step t+SLOT+4 (consumed 4 steps later)
    xq[SLOT] = *reinterpret_cast<const f32x4*>(&xp_base[SLOT * RNN_H]);
  }

  // 3) MFMA: two independent chains (even/odd kc), depth 4
  f32x4 accE = xc;
  f32x4 accO = {0.f, 0.f, 0.f, 0.f};
  __builtin_amdgcn_s_setprio(1);
#pragma unroll
  for (int kc = 0; kc < 8; kc += 2) {
    accE = __builtin_amdgcn_mfma_f32_16x16x32_bf16(wfrag[kc], hf[kc], accE, 0,
                                                   0, 0);
    accO = __builtin_amdgcn_mfma_f32_16x16x32_bf16(wfrag[kc + 1], hf[kc + 1],
                                                   accO, 0, 0, 0);
  }
  __builtin_amdgcn_s_setprio(0);

  // 4) tanh; float4 global store; packed bf16 b64 -> other LDS buffer
  f32x4 h;
#pragma unroll
  for (int r = 0; r < 4; ++r) h[r] = tanh_fast(accE[r] + accO[r]);
  if (act) {
    *reinterpret_cast<f32x4*>(&h_base[SLOT * RNN_H]) = h;
    if (last) *reinterpret_cast<f32x4*>(hl_st) = h;

    unsigned p0, p1;
    asm("v_cvt_pk_bf16_f32 %0, %1, %2" : "=v"(p0) : "v"(h[0]), "v"(h[1]));
    asm("v_cvt_pk_bf16_f32 %0, %1, %2" : "=v"(p1) : "v"(h[2]), "v"(h[3]));
    uint2 pk; pk.x = p0; pk.y = p1;
    const int byte = lrow * 512 + ((wid * 32 + lq * 8) ^ (lrow << 4));
    *reinterpret_cast<uint2*>(&hb[RD ^ 1][byte >> 1]) = pk;
  }

  // 5) LDS-only barrier (global ops remain in flight)
  wg_barrier_lds_only();
}

// ---------------------------------------------------------------------------
// Kernel 2: MFMA recurrence (byte-identical to R9). 8 WGs x 8 batches,
// 16 waves each; xp prefetched 4 steps deep.
// ---------------------------------------------------------------------------
__global__ __launch_bounds__(1024, 4) void rnn_rec_mfma(
    const float* __restrict__ Wh, const float* __restrict__ h0, float* out,
    float* h_last) {
  __shared__ unsigned short hb[2][NB * 256];

  const int bg = blockIdx.x;     // batch group 0..7
  const int tid = threadIdx.x;
  const int wid = tid >> 6;      // 0..15 = outcol tile
  const int lane = tid & 63;
  const int lrow = lane & 15;    // batch (if < NB) / A' m-index
  const int lq = lane >> 4;      // k-quad / C row-quad
  const bool act = lrow < NB;

  // ---- one-time: Wh^T A'-fragments (f32 -> bf16, RNE) into VGPRs -------
  bf16x8 wfrag[8];
  {
    const int col = wid * 16 + lrow;
#pragma unroll
    for (int kc = 0; kc < 8; ++kc) {
      bf16x8 v;
#pragma unroll
      for (int j = 0; j < 8; ++j) {
        const int k = kc * 32 + lq * 8 + j;
        v[j] = (short)f32_to_bf16_rne(Wh[(size_t)k * RNN_H + col]);
      }
      wfrag[kc] = v;
    }
  }

  // ---- one-time: h0 -> hb[0] (bf16, swizzled); 8 rows x 256 cols -------
  {
    const int b = tid >> 7;            // 0..7
    const int c0 = (tid & 127) * 2;    // 2 cols per thread
    hb[0][hidx(b, c0 + 0)] =
        f32_to_bf16_rne(h0[(size_t)(bg * NB + b) * RNN_H + c0 + 0]);
    hb[0][hidx(b, c0 + 1)] =
        f32_to_bf16_rne(h0[(size_t)(bg * NB + b) * RNN_H + c0 + 1]);
  }

  // per-lane global pointers: batch = lrow (if act), 4 consecutive cols
  float* outb = out + (size_t)bg * NB * RNN_T * RNN_H;
  const int col0 = wid * 16 + lq * 4;
  float* hbase = outb + (size_t)(lrow & 7) * RNN_T * RNN_H + col0;
  float* hl_st = h_last + (size_t)(bg * NB + (lrow & 7)) * RNN_H + col0;

  // prologue: xp rows 0..3 into the 4-slot register pipeline
  f32x4 xq[4];
  if (act) {
#pragma unroll
    for (int s = 0; s < 4; ++s)
      xq[s] = *reinterpret_cast<const f32x4*>(&hbase[s * RNN_H]);
  }
  const float* xp_base = hbase + 4 * RNN_H;  // -> xp row t+4
  float* h_base = hbase;                     // -> h row t

  wg_barrier_lds_only();  // h0 staging visible

#pragma unroll 1
  for (int t = 0; t < RNN_T; t += 4) {
    const bool lastp = (t == RNN_T - 4);
    rnn_step<0>(hb, wfrag, xq, xp_base, h_base, hl_st, false, act, lrow, lq, wid);
    rnn_step<1>(hb, wfrag, xq, xp_base, h_base, hl_st, false, act, lrow, lq, wid);
    rnn_step<2>(hb, wfrag, xq, xp_base, h_base, hl_st, false, act, lrow, lq, wid);
    rnn_step<3>(hb, wfrag, xq, xp_base, h_base, hl_st, lastp, act, lrow, lq, wid);
    xp_base += 4 * RNN_H;
    h_base += 4 * RNN_H;
  }
}

extern "C" void kernel_launch(void* const* d_in, const int* in_sizes, int n_in,
                              void* d_out, int out_size, void* d_ws, size_t ws_size,
                              hipStream_t stream) {
  const float* x = (const float*)d_in[0];
  const float* h0 = (const float*)d_in[1];
  const float* Wx = (const float*)d_in[2];
  const float* Wh = (const float*)d_in[3];
  const float* bias = (const float*)d_in[4];
  float* out = (float*)d_out;
  float* h_last = out + (size_t)RNN_B * RNN_T * RNN_H;
  unsigned short* Wxb = (unsigned short*)d_ws;  // 128 KB

  wx_prep_kernel<<<8, 1024, 0, stream>>>(Wx, Wxb);
  xp_gemm_mfma<<<RNN_B * RNN_T / GEMM_ROWS, 1024, 0, stream>>>(x, Wxb, bias,
                                                               out);
  rnn_rec_mfma<<<RNN_B / NB, 1024, 0, stream>>>(Wh, h0, out, h_last);
}

// Round 11
// 693.902 us; speedup vs baseline: 1.5239x; 1.0092x over previous
//
#include <hip/hip_runtime.h>

#define RNN_B 64
#define RNN_T 1024
#define RNN_D 256
#define RNN_H 256
#define NB 8           // batches per scan workgroup
#define GEMM_ROWS 64   // (b,t) rows per gemm block

typedef __attribute__((ext_vector_type(8))) short bf16x8;
typedef __attribute__((ext_vector_type(4))) float f32x4;

__device__ __forceinline__ unsigned short f32_to_bf16_rne(float f) {
  unsigned u = __builtin_bit_cast(unsigned, f);
  u += 0x7fffu + ((u >> 16) & 1u);
  return (unsigned short)(u >> 16);
}

// branch-free tanh: 1 - 2/(exp2(2*log2e*x)+1); exact at +/-inf, ~1e-6 abs err
// single v_mul + v_exp (trans) + v_add + v_rcp (trans) + v_fma
__device__ __forceinline__ float tanh_fast(float x) {
  const float e = x * 2.8853900817779268f;  // 2*log2(e)
  float t;
  asm("v_exp_f32 %0, %1" : "=v"(t) : "v"(e));
  const float r = __builtin_amdgcn_rcpf(t + 1.0f);
  return fmaf(-2.0f, r, 1.0f);
}

// swizzled u16 index of h[batch][col]; row stride 512B, XOR spreads rows
// across 16B bank-slots.
__device__ __forceinline__ int hidx(int batch, int col) {
  return ((batch & 7) * 512 + ((col * 2) ^ ((batch & 7) << 4))) >> 1;
}

__device__ __forceinline__ void wg_barrier_lds_only() {
  // drain LDS ops only; deliberately NOT vmcnt -> global xp prefetch and h
  // stores stay in flight across steps (avoids __syncthreads' vmcnt(0) drain)
  asm volatile("s_waitcnt lgkmcnt(0)" ::: "memory");
  __builtin_amdgcn_sched_barrier(0);
  __builtin_amdgcn_s_barrier();
  __builtin_amdgcn_sched_barrier(0);
}

// ---------------------------------------------------------------------------
// Kernel 0: Wx (f32 [k][col]) -> Wxb (bf16, fragment order [col][kc][lq][j])
// so gemm waves load A'-frags as coalesced 16B chunks.
// ---------------------------------------------------------------------------
__global__ __launch_bounds__(1024) void wx_prep_kernel(
    const float* __restrict__ Wx, unsigned short* __restrict__ Wxb) {
  const int g = blockIdx.x * 1024 + threadIdx.x;  // 8192 frags
  const int lq = g & 3;
  const int kc = (g >> 2) & 7;
  const int col = g >> 5;
  unsigned short v[8];
#pragma unroll
  for (int j = 0; j < 8; ++j) {
    const int k = kc * 32 + lq * 8 + j;
    v[j] = f32_to_bf16_rne(Wx[(size_t)k * RNN_H + col]);
  }
  *reinterpret_cast<uint4*>(&Wxb[(size_t)g * 8]) =
      *reinterpret_cast<const uint4*>(v);
}

// ---------------------------------------------------------------------------
// Kernel 1 (MFMA): xp^T = Wx^T (A', VGPRs from Wxb) x x^T (B', LDS bf16).
// 1024 blocks x 1024 thr (16 waves); block handles 64 (b,t) rows.
// At its memory roofline (~36 us incl. prep) — unchanged from R10.
// ---------------------------------------------------------------------------
__global__ __launch_bounds__(1024) void xp_gemm_mfma(
    const float* __restrict__ x, const unsigned short* __restrict__ Wxb,
    const float* __restrict__ bias, float* __restrict__ xp) {
  __shared__ unsigned short xs[GEMM_ROWS * 256];  // 32 KB

  const int tid = threadIdx.x;
  const int wid = tid >> 6;      // 0..15 = outcol tile
  const int lane = tid & 63;
  const int lrow = lane & 15;    // n-index: t-row within group
  const int lq = lane >> 4;      // k-quad / D row-quad
  const size_t row0 = (size_t)blockIdx.x * GEMM_ROWS;

  // A'-frags from Wxb: coalesced 16B loads (issue first, latency overlaps
  // with the staging below)
  bf16x8 wfrag[8];
  {
    const int col = wid * 16 + lrow;
#pragma unroll
    for (int kc = 0; kc < 8; ++kc)
      wfrag[kc] = *reinterpret_cast<const bf16x8*>(
          &Wxb[(size_t)((col * 8 + kc) * 4 + lq) * 8]);
  }
  const f32x4 bseed = *reinterpret_cast<const f32x4*>(&bias[wid * 16 + lq * 4]);

  // stage 64 x-rows as bf16 (each thread: 16 cols of one row)
  {
    const int row = tid >> 4;            // 0..63
    const int c16 = (tid & 15) * 16;     // col base
    const float* src = x + (row0 + row) * RNN_D + c16;
    unsigned p[8];
#pragma unroll
    for (int q = 0; q < 4; ++q) {
      const f32x4 v = *reinterpret_cast<const f32x4*>(src + 4 * q);
      asm("v_cvt_pk_bf16_f32 %0, %1, %2" : "=v"(p[2 * q]) : "v"(v[0]), "v"(v[1]));
      asm("v_cvt_pk_bf16_f32 %0, %1, %2" : "=v"(p[2 * q + 1]) : "v"(v[2]), "v"(v[3]));
    }
    const int swz = (row & 7) << 4;
    const int b0 = row * 512 + ((c16 * 2) ^ swz);
    const int b1 = row * 512 + ((c16 * 2 + 16) ^ swz);
    *reinterpret_cast<uint4*>(&xs[b0 >> 1]) = *reinterpret_cast<uint4*>(&p[0]);
    *reinterpret_cast<uint4*>(&xs[b1 >> 1]) = *reinterpret_cast<uint4*>(&p[4]);
  }
  __syncthreads();

#pragma unroll
  for (int rg = 0; rg < GEMM_ROWS / 16; ++rg) {
    // B'-frags: row = rg*16 + lrow, k-slice = kc*32 + lq*8 (+8)
    bf16x8 hf[8];
#pragma unroll
    for (int kc = 0; kc < 8; ++kc) {
      const int off =
          ((rg * 16 + lrow) * 512 + ((kc * 64 + lq * 16) ^ ((lrow & 7) << 4))) >> 1;
      hf[kc] = *reinterpret_cast<const bf16x8*>(&xs[off]);
    }
    f32x4 accE = bseed;
    f32x4 accO = {0.f, 0.f, 0.f, 0.f};
#pragma unroll
    for (int kc = 0; kc < 8; kc += 2) {
      accE = __builtin_amdgcn_mfma_f32_16x16x32_bf16(wfrag[kc], hf[kc], accE,
                                                     0, 0, 0);
      accO = __builtin_amdgcn_mfma_f32_16x16x32_bf16(wfrag[kc + 1], hf[kc + 1],
                                                     accO, 0, 0, 0);
    }
    const f32x4 r = accE + accO;
    float* dst = xp + (row0 + rg * 16 + lrow) * RNN_H + wid * 16 + lq * 4;
    *reinterpret_cast<f32x4*>(dst) = r;
  }
}

// ---------------------------------------------------------------------------
// One recurrence step. Swapped-operand MFMA: S^T = Wh^T (A') x h^T (B').
// 16 waves; wave wid owns ONE outcol tile. Lanes with lrow >= NB are
// exec-masked off LDS/global. Instruction diet vs R10: SINGLE 8-deep MFMA
// chain seeded with xp (C-in) — removes accO zero-init + 4 final adds;
// chain latency hides under 4 waves/SIMD. SLOT = step index in 4-step
// unroll; RD = SLOT&1 is the LDS h buffer.
// ---------------------------------------------------------------------------
template <int SLOT>
__device__ __forceinline__ void rnn_step(
    unsigned short (&hb)[2][NB * 256], const bf16x8 (&wfrag)[8],
    f32x4 (&xq)[4], const float* xp_base, float* h_base, float* hl_st,
    bool last, bool act, int lrow, int lq, int wid) {
  constexpr int RD = SLOT & 1;
  const f32x4 xc = xq[SLOT];  // consume (loaded 4 steps ago)

  // 1) B'-fragments of h from LDS first (critical path), masked to NB rows
  bf16x8 hf[8];
  if (act) {
#pragma unroll
    for (int kc = 0; kc < 8; ++kc) {
      const int off = (lrow * 512 + ((kc * 64 + lq * 16) ^ (lrow << 4))) >> 1;
      hf[kc] = *reinterpret_cast<const bf16x8*>(&hb[RD][off]);
    }
    // 2) refill slot: prefetch xp for step t+SLOT+4 (consumed 4 steps later)
    xq[SLOT] = *reinterpret_cast<const f32x4*>(&xp_base[SLOT * RNN_H]);
  }

  // 3) MFMA: single chain of 8, seeded with xp
  f32x4 acc = xc;
  __builtin_amdgcn_s_setprio(1);
#pragma unroll
  for (int kc = 0; kc < 8; ++kc)
    acc = __builtin_amdgcn_mfma_f32_16x16x32_bf16(wfrag[kc], hf[kc], acc, 0, 0,
                                                  0);
  __builtin_amdgcn_s_setprio(0);

  // 4) tanh; float4 global store; packed bf16 b64 -> other LDS buffer
  f32x4 h;
#pragma unroll
  for (int r = 0; r < 4; ++r) h[r] = tanh_fast(acc[r]);
  if (act) {
    *reinterpret_cast<f32x4*>(&h_base[SLOT * RNN_H]) = h;
    if (last) *reinterpret_cast<f32x4*>(hl_st) = h;

    unsigned p0, p1;
    asm("v_cvt_pk_bf16_f32 %0, %1, %2" : "=v"(p0) : "v"(h[0]), "v"(h[1]));
    asm("v_cvt_pk_bf16_f32 %0, %1, %2" : "=v"(p1) : "v"(h[2]), "v"(h[3]));
    uint2 pk; pk.x = p0; pk.y = p1;
    const int byte = lrow * 512 + ((wid * 32 + lq * 8) ^ (lrow << 4));
    *reinterpret_cast<uint2*>(&hb[RD ^ 1][byte >> 1]) = pk;
  }

  // 5) LDS-only barrier (global ops remain in flight)
  wg_barrier_lds_only();
}

// ---------------------------------------------------------------------------
// Kernel 2: MFMA recurrence. 8 WGs x 8 batches, 16 waves (1024 thr) each;
// xp prefetched 4 steps deep.
// ---------------------------------------------------------------------------
__global__ __launch_bounds__(1024, 4) void rnn_rec_mfma(
    const float* __restrict__ Wh, const float* __restrict__ h0, float* out,
    float* h_last) {
  __shared__ unsigned short hb[2][NB * 256];

  const int bg = blockIdx.x;     // batch group 0..7
  const int tid = threadIdx.x;
  const int wid = tid >> 6;      // 0..15 = outcol tile
  const int lane = tid & 63;
  const int lrow = lane & 15;    // batch (if < NB) / A' m-index
  const int lq = lane >> 4;      // k-quad / C row-quad
  const bool act = lrow < NB;

  // ---- one-time: Wh^T A'-fragments (f32 -> bf16, RNE) into VGPRs -------
  bf16x8 wfrag[8];
  {
    const int col = wid * 16 + lrow;
#pragma unroll
    for (int kc = 0; kc < 8; ++kc) {
      bf16x8 v;
#pragma unroll
      for (int j = 0; j < 8; ++j) {
        const int k = kc * 32 + lq * 8 + j;
        v[j] = (short)f32_to_bf16_rne(Wh[(size_t)k * RNN_H + col]);
      }
      wfrag[kc] = v;
    }
  }

  // ---- one-time: h0 -> hb[0] (bf16, swizzled); 8 rows x 256 cols -------
  {
    const int b = tid >> 7;            // 0..7
    const int c0 = (tid & 127) * 2;    // 2 cols per thread
    hb[0][hidx(b, c0 + 0)] =
        f32_to_bf16_rne(h0[(size_t)(bg * NB + b) * RNN_H + c0 + 0]);
    hb[0][hidx(b, c0 + 1)] =
        f32_to_bf16_rne(h0[(size_t)(bg * NB + b) * RNN_H + c0 + 1]);
  }

  // per-lane global pointers: batch = lrow (if act), 4 consecutive cols
  float* outb = out + (size_t)bg * NB * RNN_T * RNN_H;
  const int col0 = wid * 16 + lq * 4;
  float* hbase = outb + (size_t)(lrow & 7) * RNN_T * RNN_H + col0;
  float* hl_st = h_last + (size_t)(bg * NB + (lrow & 7)) * RNN_H + col0;

  // prologue: xp rows 0..3 into the 4-slot register pipeline
  f32x4 xq[4];
  if (act) {
#pragma unroll
    for (int s = 0; s < 4; ++s)
      xq[s] = *reinterpret_cast<const f32x4*>(&hbase[s * RNN_H]);
  }
  const float* xp_base = hbase + 4 * RNN_H;  // -> xp row t+4
  float* h_base = hbase;                     // -> h row t

  wg_barrier_lds_only();  // h0 staging visible

#pragma unroll 1
  for (int t = 0; t < RNN_T; t += 4) {
    const bool lastp = (t == RNN_T - 4);
    rnn_step<0>(hb, wfrag, xq, xp_base, h_base, hl_st, false, act, lrow, lq, wid);
    rnn_step<1>(hb, wfrag, xq, xp_base, h_base, hl_st, false, act, lrow, lq, wid);
    rnn_step<2>(hb, wfrag, xq, xp_base, h_base, hl_st, false, act, lrow, lq, wid);
    rnn_step<3>(hb, wfrag, xq, xp_base, h_base, hl_st, lastp, act, lrow, lq, wid);
    xp_base += 4 * RNN_H;
    h_base += 4 * RNN_H;
  }
}

extern "C" void kernel_launch(void* const* d_in, const int* in_sizes, int n_in,
                              void* d_out, int out_size, void* d_ws, size_t ws_size,
                              hipStream_t stream) {
  const float* x = (const float*)d_in[0];
  const float* h0 = (const float*)d_in[1];
  const float* Wx = (const float*)d_in[2];
  const float* Wh = (const float*)d_in[3];
  const float* bias = (const float*)d_in[4];
  float* out = (float*)d_out;
  float* h_last = out + (size_t)RNN_B * RNN_T * RNN_H;
  unsigned short* Wxb = (unsigned short*)d_ws;  // 128 KB

  wx_prep_kernel<<<8, 1024, 0, stream>>>(Wx, Wxb);
  xp_gemm_mfma<<<RNN_B * RNN_T / GEMM_ROWS, 1024, 0, stream>>>(x, Wxb, bias,
                                                               out);
  rnn_rec_mfma<<<RNN_B / NB, 1024, 0, stream>>>(Wh, h0, out, h_last);
}

// Round 12
// 649.273 us; speedup vs baseline: 1.6287x; 1.0687x over previous
//
#include <hip/hip_runtime.h>

#define RNN_B 64
#define RNN_T 1024
#define RNN_D 256
#define RNN_H 256
#define NB 4           // batches per scan workgroup (16 WGs)
#define GEMM_ROWS 64   // (b,t) rows per gemm block

typedef __attribute__((ext_vector_type(8))) short bf16x8;
typedef __attribute__((ext_vector_type(4))) float f32x4;

__device__ __forceinline__ unsigned short f32_to_bf16_rne(float f) {
  unsigned u = __builtin_bit_cast(unsigned, f);
  u += 0x7fffu + ((u >> 16) & 1u);
  return (unsigned short)(u >> 16);
}

// branch-free tanh: 1 - 2/(exp2(2*log2e*x)+1); exact at +/-inf, ~1e-6 abs err
__device__ __forceinline__ float tanh_fast(float x) {
  const float e = x * 2.8853900817779268f;  // 2*log2(e)
  float t;
  asm("v_exp_f32 %0, %1" : "=v"(t) : "v"(e));
  const float r = __builtin_amdgcn_rcpf(t + 1.0f);
  return fmaf(-2.0f, r, 1.0f);
}

// swizzled u16 index of h[batch][col]; row stride 512B, XOR spreads rows
// across 16B bank-slots.
__device__ __forceinline__ int hidx(int batch, int col) {
  return ((batch & 7) * 512 + ((col * 2) ^ ((batch & 7) << 4))) >> 1;
}

__device__ __forceinline__ void wg_barrier_lds_only() {
  // drain LDS ops only; deliberately NOT vmcnt -> global xp prefetch and h
  // stores stay in flight across steps (avoids __syncthreads' vmcnt(0) drain)
  asm volatile("s_waitcnt lgkmcnt(0)" ::: "memory");
  __builtin_amdgcn_sched_barrier(0);
  __builtin_amdgcn_s_barrier();
  __builtin_amdgcn_sched_barrier(0);
}

// ---------------------------------------------------------------------------
// Kernel 0: Wx (f32 [k][col]) -> Wxb (bf16, fragment order [col][kc][lq][j])
// so gemm waves load A'-frags as coalesced 16B chunks.
// ---------------------------------------------------------------------------
__global__ __launch_bounds__(1024) void wx_prep_kernel(
    const float* __restrict__ Wx, unsigned short* __restrict__ Wxb) {
  const int g = blockIdx.x * 1024 + threadIdx.x;  // 8192 frags
  const int lq = g & 3;
  const int kc = (g >> 2) & 7;
  const int col = g >> 5;
  unsigned short v[8];
#pragma unroll
  for (int j = 0; j < 8; ++j) {
    const int k = kc * 32 + lq * 8 + j;
    v[j] = f32_to_bf16_rne(Wx[(size_t)k * RNN_H + col]);
  }
  *reinterpret_cast<uint4*>(&Wxb[(size_t)g * 8]) =
      *reinterpret_cast<const uint4*>(v);
}

// ---------------------------------------------------------------------------
// Kernel 1 (MFMA): xp^T = Wx^T (A', VGPRs from Wxb) x x^T (B', LDS bf16).
// 1024 blocks x 1024 thr (16 waves); block handles 64 (b,t) rows.
// At its memory roofline (~36 us incl. prep) — unchanged from R10.
// ---------------------------------------------------------------------------
__global__ __launch_bounds__(1024) void xp_gemm_mfma(
    const float* __restrict__ x, const unsigned short* __restrict__ Wxb,
    const float* __restrict__ bias, float* __restrict__ xp) {
  __shared__ unsigned short xs[GEMM_ROWS * 256];  // 32 KB

  const int tid = threadIdx.x;
  const int wid = tid >> 6;      // 0..15 = outcol tile
  const int lane = tid & 63;
  const int lrow = lane & 15;    // n-index: t-row within group
  const int lq = lane >> 4;      // k-quad / D row-quad
  const size_t row0 = (size_t)blockIdx.x * GEMM_ROWS;

  // A'-frags from Wxb: coalesced 16B loads (issue first, latency overlaps
  // with the staging below)
  bf16x8 wfrag[8];
  {
    const int col = wid * 16 + lrow;
#pragma unroll
    for (int kc = 0; kc < 8; ++kc)
      wfrag[kc] = *reinterpret_cast<const bf16x8*>(
          &Wxb[(size_t)((col * 8 + kc) * 4 + lq) * 8]);
  }
  const f32x4 bseed = *reinterpret_cast<const f32x4*>(&bias[wid * 16 + lq * 4]);

  // stage 64 x-rows as bf16 (each thread: 16 cols of one row)
  {
    const int row = tid >> 4;            // 0..63
    const int c16 = (tid & 15) * 16;     // col base
    const float* src = x + (row0 + row) * RNN_D + c16;
    unsigned p[8];
#pragma unroll
    for (int q = 0; q < 4; ++q) {
      const f32x4 v = *reinterpret_cast<const f32x4*>(src + 4 * q);
      asm("v_cvt_pk_bf16_f32 %0, %1, %2" : "=v"(p[2 * q]) : "v"(v[0]), "v"(v[1]));
      asm("v_cvt_pk_bf16_f32 %0, %1, %2" : "=v"(p[2 * q + 1]) : "v"(v[2]), "v"(v[3]));
    }
    const int swz = (row & 7) << 4;
    const int b0 = row * 512 + ((c16 * 2) ^ swz);
    const int b1 = row * 512 + ((c16 * 2 + 16) ^ swz);
    *reinterpret_cast<uint4*>(&xs[b0 >> 1]) = *reinterpret_cast<uint4*>(&p[0]);
    *reinterpret_cast<uint4*>(&xs[b1 >> 1]) = *reinterpret_cast<uint4*>(&p[4]);
  }
  __syncthreads();

#pragma unroll
  for (int rg = 0; rg < GEMM_ROWS / 16; ++rg) {
    // B'-frags: row = rg*16 + lrow, k-slice = kc*32 + lq*8 (+8)
    bf16x8 hf[8];
#pragma unroll
    for (int kc = 0; kc < 8; ++kc) {
      const int off =
          ((rg * 16 + lrow) * 512 + ((kc * 64 + lq * 16) ^ ((lrow & 7) << 4))) >> 1;
      hf[kc] = *reinterpret_cast<const bf16x8*>(&xs[off]);
    }
    f32x4 accE = bseed;
    f32x4 accO = {0.f, 0.f, 0.f, 0.f};
#pragma unroll
    for (int kc = 0; kc < 8; kc += 2) {
      accE = __builtin_amdgcn_mfma_f32_16x16x32_bf16(wfrag[kc], hf[kc], accE,
                                                     0, 0, 0);
      accO = __builtin_amdgcn_mfma_f32_16x16x32_bf16(wfrag[kc + 1], hf[kc + 1],
                                                     accO, 0, 0, 0);
    }
    const f32x4 r = accE + accO;
    float* dst = xp + (row0 + rg * 16 + lrow) * RNN_H + wid * 16 + lq * 4;
    *reinterpret_cast<f32x4*>(dst) = r;
  }
}

// ---------------------------------------------------------------------------
// One recurrence step. Swapped-operand MFMA: S^T = Wh^T (A') x h^T (B').
// 16 waves; wave wid owns ONE outcol tile. Lanes with lrow >= NB are
// exec-masked off LDS/global (their MFMA output is garbage, never stored).
// acc = single 8-deep MFMA chain seeded with xp (C-in). SLOT = step index
// in 4-step unroll; RD = SLOT&1 is the LDS h buffer.
// ---------------------------------------------------------------------------
template <int SLOT>
__device__ __forceinline__ void rnn_step(
    unsigned short (&hb)[2][NB * 256], const bf16x8 (&wfrag)[8],
    f32x4 (&xq)[4], const float* xp_base, float* h_base, float* hl_st,
    bool last, bool act, int lrow, int lq, int wid) {
  constexpr int RD = SLOT & 1;
  const f32x4 xc = xq[SLOT];  // consume (loaded 4 steps ago)

  // 1) B'-fragments of h from LDS first (critical path), masked to NB rows
  bf16x8 hf[8];
  if (act) {
#pragma unroll
    for (int kc = 0; kc < 8; ++kc) {
      const int off = (lrow * 512 + ((kc * 64 + lq * 16) ^ (lrow << 4))) >> 1;
      hf[kc] = *reinterpret_cast<const bf16x8*>(&hb[RD][off]);
    }
    // 2) refill slot: prefetch xp for step t+SLOT+4 (consumed 4 steps later)
    xq[SLOT] = *reinterpret_cast<const f32x4*>(&xp_base[SLOT * RNN_H]);
  }

  // 3) MFMA: single chain of 8, seeded with xp
  f32x4 acc = xc;
  __builtin_amdgcn_s_setprio(1);
#pragma unroll
  for (int kc = 0; kc < 8; ++kc)
    acc = __builtin_amdgcn_mfma_f32_16x16x32_bf16(wfrag[kc], hf[kc], acc, 0, 0,
                                                  0);
  __builtin_amdgcn_s_setprio(0);

  // 4) tanh; float4 global store; packed bf16 b64 -> other LDS buffer
  f32x4 h;
#pragma unroll
  for (int r = 0; r < 4; ++r) h[r] = tanh_fast(acc[r]);
  if (act) {
    *reinterpret_cast<f32x4*>(&h_base[SLOT * RNN_H]) = h;
    if (last) *reinterpret_cast<f32x4*>(hl_st) = h;

    unsigned p0, p1;
    asm("v_cvt_pk_bf16_f32 %0, %1, %2" : "=v"(p0) : "v"(h[0]), "v"(h[1]));
    asm("v_cvt_pk_bf16_f32 %0, %1, %2" : "=v"(p1) : "v"(h[2]), "v"(h[3]));
    uint2 pk; pk.x = p0; pk.y = p1;
    const int byte = lrow * 512 + ((wid * 32 + lq * 8) ^ (lrow << 4));
    *reinterpret_cast<uint2*>(&hb[RD ^ 1][byte >> 1]) = pk;
  }

  // 5) LDS-only barrier (global ops remain in flight)
  wg_barrier_lds_only();
}

// ---------------------------------------------------------------------------
// Kernel 2: MFMA recurrence. 16 WGs x 4 batches, 16 waves (1024 thr) each;
// xp prefetched 4 steps deep. Halved per-CU LDS read volume vs NB=8.
// ---------------------------------------------------------------------------
__global__ __launch_bounds__(1024, 4) void rnn_rec_mfma(
    const float* __restrict__ Wh, const float* __restrict__ h0, float* out,
    float* h_last) {
  __shared__ unsigned short hb[2][NB * 256];

  const int bg = blockIdx.x;     // batch group 0..15
  const int tid = threadIdx.x;
  const int wid = tid >> 6;      // 0..15 = outcol tile
  const int lane = tid & 63;
  const int lrow = lane & 15;    // batch (if < NB) / A' m-index
  const int lq = lane >> 4;      // k-quad / C row-quad
  const bool act = lrow < NB;

  // ---- one-time: Wh^T A'-fragments (f32 -> bf16, RNE) into VGPRs -------
  bf16x8 wfrag[8];
  {
    const int col = wid * 16 + lrow;
#pragma unroll
    for (int kc = 0; kc < 8; ++kc) {
      bf16x8 v;
#pragma unroll
      for (int j = 0; j < 8; ++j) {
        const int k = kc * 32 + lq * 8 + j;
        v[j] = (short)f32_to_bf16_rne(Wh[(size_t)k * RNN_H + col]);
      }
      wfrag[kc] = v;
    }
  }

  // ---- one-time: h0 -> hb[0] (bf16, swizzled); NB rows x 256 cols ------
  {
    const int b = tid >> 8;            // 0..3
    const int c = tid & 255;           // col
    hb[0][hidx(b, c)] =
        f32_to_bf16_rne(h0[(size_t)(bg * NB + b) * RNN_H + c]);
  }

  // per-lane global pointers: batch = lrow (if act), 4 consecutive cols
  float* outb = out + (size_t)bg * NB * RNN_T * RNN_H;
  const int col0 = wid * 16 + lq * 4;
  float* hbase = outb + (size_t)(lrow & (NB - 1)) * RNN_T * RNN_H + col0;
  float* hl_st = h_last + (size_t)(bg * NB + (lrow & (NB - 1))) * RNN_H + col0;

  // prologue: xp rows 0..3 into the 4-slot register pipeline
  f32x4 xq[4];
  if (act) {
#pragma unroll
    for (int s = 0; s < 4; ++s)
      xq[s] = *reinterpret_cast<const f32x4*>(&hbase[s * RNN_H]);
  }
  const float* xp_base = hbase + 4 * RNN_H;  // -> xp row t+4
  float* h_base = hbase;                     // -> h row t

  wg_barrier_lds_only();  // h0 staging visible

#pragma unroll 1
  for (int t = 0; t < RNN_T; t += 4) {
    const bool lastp = (t == RNN_T - 4);
    rnn_step<0>(hb, wfrag, xq, xp_base, h_base, hl_st, false, act, lrow, lq, wid);
    rnn_step<1>(hb, wfrag, xq, xp_base, h_base, hl_st, false, act, lrow, lq, wid);
    rnn_step<2>(hb, wfrag, xq, xp_base, h_base, hl_st, false, act, lrow, lq, wid);
    rnn_step<3>(hb, wfrag, xq, xp_base, h_base, hl_st, lastp, act, lrow, lq, wid);
    xp_base += 4 * RNN_H;
    h_base += 4 * RNN_H;
  }
}

extern "C" void kernel_launch(void* const* d_in, const int* in_sizes, int n_in,
                              void* d_out, int out_size, void* d_ws, size_t ws_size,
                              hipStream_t stream) {
  const float* x = (const float*)d_in[0];
  const float* h0 = (const float*)d_in[1];
  const float* Wx = (const float*)d_in[2];
  const float* Wh = (const float*)d_in[3];
  const float* bias = (const float*)d_in[4];
  float* out = (float*)d_out;
  float* h_last = out + (size_t)RNN_B * RNN_T * RNN_H;
  unsigned short* Wxb = (unsigned short*)d_ws;  // 128 KB

  wx_prep_kernel<<<8, 1024, 0, stream>>>(Wx, Wxb);
  xp_gemm_mfma<<<RNN_B * RNN_T / GEMM_ROWS, 1024, 0, stream>>>(x, Wxb, bias,
                                                               out);
  rnn_rec_mfma<<<RNN_B / NB, 1024, 0, stream>>>(Wh, h0, out, h_last);
}